// Round 1
// baseline (545.176 us; speedup 1.0000x reference)
//
#include <hip/hip_runtime.h>

// LaneATT head, MI355X. Pipeline:
//  prep (bf16 weights, x-index table) -> conv1x1 -> gather(baf bf16, padded 1024x768)
//  -> GEMM1 scores (bf16 MFMA) -> softmax+shift (in-place) -> transpose baf
//  -> GEMM2 att_feat -> GEMM3 (cls|reg) + epilogue into d_out.
// ws layout (bytes, 256-aligned), total 221,617,152:
//  feat 0 (1.8M) | xn 1802240 (44K, [11004]=mask-dtype flag) | attn_wb 1846272 (1.44M)
//  | wcat 3288064 (225K) | baf 3513344 (50.3M) | bafT 53844992 (50.3M)
//  | att 104176640 (67.1M) | att_feat 171285504 (50.3M)

typedef unsigned short u16;
typedef short short8 __attribute__((ext_vector_type(8)));
typedef float f32x4 __attribute__((ext_vector_type(4)));

__device__ __forceinline__ u16 f2bf(float f) {
    union { float f; unsigned u; } v; v.f = f;
    unsigned r = v.u + 0x7FFFu + ((v.u >> 16) & 1u);
    return (u16)(r >> 16);
}
__device__ __forceinline__ float bf2f(u16 u) {
    union { unsigned u; float f; } v; v.u = ((unsigned)u) << 16;
    return v.f;
}

// ---------- prep kernels ----------

__global__ __launch_bounds__(256) void k_prep_attnw(const float* __restrict__ attn_w,
                                                    u16* __restrict__ attn_wb) {
    int i = blockIdx.x * 256 + threadIdx.x;          // over 1024*704
    if (i >= 1024 * 704) return;
    int r = i / 704;
    attn_wb[i] = (r < 999) ? f2bf(attn_w[i]) : (u16)0;
}

__global__ __launch_bounds__(256) void k_prep_wcat(const float* __restrict__ cls_w,
                                                   const float* __restrict__ reg_w,
                                                   u16* __restrict__ wcat) {
    int i = blockIdx.x * 256 + threadIdx.x;          // over 80*1408
    if (i >= 80 * 1408) return;
    int o = i / 1408, k = i - o * 1408;
    float v = 0.f;
    if (o < 2) v = cls_w[o * 1408 + k];
    else if (o < 75) v = reg_w[(o - 2) * 1408 + k];
    wcat[i] = f2bf(v);
}

// Detect whether invalid_mask was pushed as bool (1B) or int32 (4B):
// int32 0/1 values have all bytes at i%4!=0 == 0; real bool data (~29% ones)
// will have nonzero bytes there with probability ~1.
__global__ __launch_bounds__(256) void k_detect_mask(const unsigned char* __restrict__ mask,
                                                     int* __restrict__ flag) {
    int any = 0;
    for (int i = threadIdx.x; i < 11000; i += 256)
        if ((i & 3) && mask[i]) any = 1;
    any = __any(any) ? 1 : 0;
    __shared__ int sh[4];
    if ((threadIdx.x & 63) == 0) sh[threadIdx.x >> 6] = any;
    __syncthreads();
    if (threadIdx.x == 0) *flag = sh[0] | sh[1] | sh[2] | sh[3];
}

__global__ __launch_bounds__(256) void k_prep_xn(const int* __restrict__ cut_xs,
                                                 const void* __restrict__ mask,
                                                 const int* __restrict__ flag,
                                                 int* __restrict__ xn) {
    int i = blockIdx.x * 256 + threadIdx.x;          // over 11000 = (n,y)
    if (i >= 11000) return;
    int inv = (*flag) ? (int)((const unsigned char*)mask)[i]
                      : ((const int*)mask)[i];
    int n = i / 11, y = i - n * 11;
    xn[i] = inv ? -1 : cut_xs[n * 704 + y];          // cut_xs[(n*64+0)*11+y]
}

// ---------- conv 1x1 ----------
__global__ __launch_bounds__(256) void k_conv(const float* __restrict__ x,
                                              const float* __restrict__ w1,
                                              const float* __restrict__ b1,
                                              float* __restrict__ feat) {
    __shared__ float wl[16][512];
    int b = blockIdx.x, ot = blockIdx.y;             // ot in [0,4): 16 out-ch each
    for (int i = threadIdx.x; i < 16 * 512; i += 256)
        wl[i >> 9][i & 511] = w1[(ot * 16 + (i >> 9)) * 512 + (i & 511)];
    __syncthreads();
    const float* xb = x + (size_t)b * 512 * 220;
    for (int idx = threadIdx.x; idx < 16 * 220; idx += 256) {
        int o = idx / 220, p = idx - o * 220;
        float acc = 0.f;
        #pragma unroll 8
        for (int c = 0; c < 512; ++c) acc = fmaf(xb[c * 220 + p], wl[o][c], acc);
        feat[(size_t)b * 14080 + (ot * 16 + o) * 220 + p] = acc + b1[ot * 16 + o];
    }
}

// ---------- gather -> baf (bf16, [B][1024][768], pads zeroed) ----------
__global__ __launch_bounds__(256) void k_gather(const float* __restrict__ feat,
                                                const int* __restrict__ xn,
                                                u16* __restrict__ baf) {
    int n = blockIdx.x, b = blockIdx.y;
    u16* dst = baf + ((size_t)b * 1024 + n) * 768;
    const float* fb = feat + (size_t)b * 14080;
    for (int d = threadIdx.x; d < 768; d += 256) {
        float v = 0.f;
        if (n < 1000 && d < 704) {
            int c = d / 11, y = d - c * 11;
            int xv = xn[n * 11 + y];
            if (xv >= 0) v = fb[c * 220 + y * 20 + xv];
        }
        dst[d] = f2bf(v);
    }
}

// ---------- generic 128x128 bf16 GEMM, C = A(MxK) * Bt(NrowsxK)^T ----------
__global__ __launch_bounds__(256) void k_gemm(const u16* __restrict__ A, long sAb, int lda,
                                              const u16* __restrict__ Bt, long sBb, int ldb,
                                              u16* __restrict__ C, long sCb, int ldc,
                                              int ntN, int ksteps) {
    __shared__ __attribute__((aligned(16))) u16 Al[128 * 32];
    __shared__ __attribute__((aligned(16))) u16 Bl[128 * 32];
    A  += (size_t)blockIdx.y * sAb;
    Bt += (size_t)blockIdx.y * sBb;
    C  += (size_t)blockIdx.y * sCb;
    const int tid = threadIdx.x;
    const int tM = blockIdx.x / ntN, tN = blockIdx.x - tM * ntN;
    const int lane = tid & 63, w = tid >> 6;
    const int wr = w >> 1, wc = w & 1;
    const int l15 = lane & 15, lk = (lane >> 4) * 8;

    const u16* Abase = A + (size_t)tM * 128 * lda;
    const u16* Bbase = Bt + (size_t)tN * 128 * ldb;

    f32x4 acc[4][4] = {};

    for (int ks = 0; ks < ksteps; ++ks) {
        const int k0 = ks * 32;
        #pragma unroll
        for (int i = 0; i < 2; ++i) {
            int chunk = i * 256 + tid;
            int row = chunk >> 2, c8 = (chunk & 3) * 8;
            short8 va = *(const short8*)(Abase + (size_t)row * lda + k0 + c8);
            short8 vb = *(const short8*)(Bbase + (size_t)row * ldb + k0 + c8);
            *(short8*)&Al[chunk * 8] = va;
            *(short8*)&Bl[chunk * 8] = vb;
        }
        __syncthreads();
        short8 af[4], bfr[4];
        #pragma unroll
        for (int m = 0; m < 4; ++m) af[m] = *(const short8*)&Al[(wr * 64 + m * 16 + l15) * 32 + lk];
        #pragma unroll
        for (int n = 0; n < 4; ++n) bfr[n] = *(const short8*)&Bl[(wc * 64 + n * 16 + l15) * 32 + lk];
        #pragma unroll
        for (int m = 0; m < 4; ++m)
            #pragma unroll
            for (int n = 0; n < 4; ++n)
                acc[m][n] = __builtin_amdgcn_mfma_f32_16x16x32_bf16(af[m], bfr[n], acc[m][n], 0, 0, 0);
        __syncthreads();
    }

    const int rb = tM * 128 + wr * 64 + ((lane >> 4) << 2);
    const int cb = tN * 128 + wc * 64 + l15;
    #pragma unroll
    for (int m = 0; m < 4; ++m)
        #pragma unroll
        for (int n = 0; n < 4; ++n)
            #pragma unroll
            for (int j = 0; j < 4; ++j)
                C[(size_t)(rb + m * 16 + j) * ldc + cb + n * 16] = f2bf(acc[m][n][j]);
}

// ---------- softmax + diagonal-shift scatter, in-place on att rows ----------
__global__ __launch_bounds__(256) void k_softmax(u16* __restrict__ att,
                                                 const float* __restrict__ attn_b) {
    __shared__ float sv[1000];
    __shared__ float redm[4], reds[4];
    u16* row = att + (size_t)blockIdx.x * 1024;
    const int n = blockIdx.x & 1023;
    const int tid = threadIdx.x;
    if (n >= 1000) {
        for (int i = tid; i < 1024; i += 256) row[i] = 0;
        return;
    }
    float lmax = -1e30f;
    for (int i = tid; i < 999; i += 256) {
        float v = bf2f(row[i]) + attn_b[i];
        sv[i] = v;
        lmax = fmaxf(lmax, v);
    }
    #pragma unroll
    for (int o = 32; o > 0; o >>= 1) lmax = fmaxf(lmax, __shfl_xor(lmax, o));
    if ((tid & 63) == 0) redm[tid >> 6] = lmax;
    __syncthreads();
    float gmax = fmaxf(fmaxf(redm[0], redm[1]), fmaxf(redm[2], redm[3]));
    float lsum = 0.f;
    for (int i = tid; i < 999; i += 256) {
        float e = __expf(sv[i] - gmax);
        sv[i] = e;
        lsum += e;
    }
    #pragma unroll
    for (int o = 32; o > 0; o >>= 1) lsum += __shfl_xor(lsum, o);
    if ((tid & 63) == 0) reds[tid >> 6] = lsum;
    __syncthreads();
    float inv = 1.f / (reds[0] + reds[1] + reds[2] + reds[3]);
    for (int col = tid; col < 1024; col += 256) {
        u16 v = 0;
        if (col < 1000 && col != n) {
            int m = col - (col > n ? 1 : 0);
            v = f2bf(sv[m] * inv);
        }
        row[col] = v;
    }
}

// ---------- baf transpose: bafT[b][d][m] = baf[b][m][d] ----------
__global__ __launch_bounds__(256) void k_transpose(const u16* __restrict__ baf,
                                                   u16* __restrict__ bafT) {
    __shared__ u16 t[64][65];
    int mt = blockIdx.x & 15, dt = blockIdx.x >> 4;  // 16 m-tiles x 12 d-tiles
    int b = blockIdx.y;
    const u16* src = baf + ((size_t)b * 1024 + mt * 64) * 768 + dt * 64;
    for (int i = threadIdx.x; i < 4096; i += 256) {
        int ml = i >> 6, dl = i & 63;
        t[ml][dl] = src[(size_t)ml * 768 + dl];
    }
    __syncthreads();
    u16* dst = bafT + ((size_t)b * 768 + dt * 64) * 1024 + mt * 64;
    for (int i = threadIdx.x; i < 4096; i += 256) {
        int dl = i >> 6, ml = i & 63;
        dst[(size_t)dl * 1024 + ml] = t[ml][dl];
    }
}

// ---------- final GEMM (all_feat x Wcat^T) + output assembly ----------
__global__ __launch_bounds__(256) void k_gemm3(const u16* __restrict__ AF,
                                               const u16* __restrict__ BAF,
                                               const u16* __restrict__ W,
                                               const float* __restrict__ anchors,
                                               const float* __restrict__ cls_b,
                                               const float* __restrict__ reg_b,
                                               float* __restrict__ out) {
    __shared__ __attribute__((aligned(16))) u16 Al[128 * 32];
    __shared__ __attribute__((aligned(16))) u16 Bl[80 * 32];
    const int tid = threadIdx.x;
    const int tM = blockIdx.x;
    const int lane = tid & 63, w = tid >> 6;
    const int l15 = lane & 15, lk = (lane >> 4) * 8;

    f32x4 acc[2][5] = {};

    for (int ks = 0; ks < 44; ++ks) {
        const u16* Asrc = (ks < 22) ? AF : BAF;
        const int k0 = (ks < 22 ? ks : ks - 22) * 32;
        #pragma unroll
        for (int i = 0; i < 2; ++i) {
            int chunk = i * 256 + tid;
            int row = chunk >> 2, c8 = (chunk & 3) * 8;
            *(short8*)&Al[chunk * 8] =
                *(const short8*)(Asrc + (size_t)(tM * 128 + row) * 768 + k0 + c8);
        }
        {
            int row = tid >> 2, c8 = (tid & 3) * 8;
            *(short8*)&Bl[tid * 8] = *(const short8*)(W + (size_t)row * 1408 + ks * 32 + c8);
            if (tid < 64) {
                int ch2 = 256 + tid;
                int r2 = ch2 >> 2, c82 = (ch2 & 3) * 8;
                *(short8*)&Bl[ch2 * 8] = *(const short8*)(W + (size_t)r2 * 1408 + ks * 32 + c82);
            }
        }
        __syncthreads();
        short8 af[2], bfr[5];
        #pragma unroll
        for (int m = 0; m < 2; ++m) af[m] = *(const short8*)&Al[(w * 32 + m * 16 + l15) * 32 + lk];
        #pragma unroll
        for (int n = 0; n < 5; ++n) bfr[n] = *(const short8*)&Bl[(n * 16 + l15) * 32 + lk];
        #pragma unroll
        for (int m = 0; m < 2; ++m)
            #pragma unroll
            for (int n = 0; n < 5; ++n)
                acc[m][n] = __builtin_amdgcn_mfma_f32_16x16x32_bf16(af[m], bfr[n], acc[m][n], 0, 0, 0);
        __syncthreads();
    }

    #pragma unroll
    for (int m = 0; m < 2; ++m) {
        #pragma unroll
        for (int n = 0; n < 5; ++n) {
            #pragma unroll
            for (int j = 0; j < 4; ++j) {
                int r = tM * 128 + w * 32 + m * 16 + ((lane >> 4) << 2) + j;
                int b = r >> 10, nn = r & 1023;
                if (nn < 1000) {
                    int o = n * 16 + l15;
                    float v = acc[m][n][j];
                    float* orow = out + ((size_t)b * 1000 + nn) * 77;
                    if (o < 2) {
                        orow[o] = v + cls_b[o];
                    } else if (o < 75) {
                        int jj = o - 2;
                        orow[4 + jj] = v + reg_b[jj] + anchors[nn * 77 + 4 + jj];
                        if (o == 2) orow[2] = anchors[nn * 77 + 2];
                        if (o == 3) orow[3] = anchors[nn * 77 + 3];
                    }
                }
            }
        }
    }
}

extern "C" void kernel_launch(void* const* d_in, const int* in_sizes, int n_in,
                              void* d_out, int out_size, void* d_ws, size_t ws_size,
                              hipStream_t stream) {
    const float* x       = (const float*)d_in[0];
    const float* anchors = (const float*)d_in[1];
    const float* conv1_w = (const float*)d_in[2];
    const float* conv1_b = (const float*)d_in[3];
    const float* attn_w  = (const float*)d_in[4];
    const float* attn_b  = (const float*)d_in[5];
    const float* cls_w   = (const float*)d_in[6];
    const float* cls_b   = (const float*)d_in[7];
    const float* reg_w   = (const float*)d_in[8];
    const float* reg_b   = (const float*)d_in[9];
    const int*   cut_xs  = (const int*)d_in[12];
    const void*  invalid = d_in[13];
    float* out = (float*)d_out;

    char* ws = (char*)d_ws;
    float* feat    = (float*)(ws + 0);
    int*   xn      = (int*)  (ws + 1802240);
    int*   mflag   = xn + 11004;
    u16*   attn_wb = (u16*)  (ws + 1846272);
    u16*   wcat    = (u16*)  (ws + 3288064);
    u16*   baf     = (u16*)  (ws + 3513344);
    u16*   bafT    = (u16*)  (ws + 53844992);
    u16*   att     = (u16*)  (ws + 104176640);
    u16*   att_feat= (u16*)  (ws + 171285504);

    k_prep_attnw<<<2816, 256, 0, stream>>>(attn_w, attn_wb);
    k_prep_wcat<<<440, 256, 0, stream>>>(cls_w, reg_w, wcat);
    k_detect_mask<<<1, 256, 0, stream>>>((const unsigned char*)invalid, mflag);
    k_prep_xn<<<43, 256, 0, stream>>>(cut_xs, invalid, mflag, xn);
    k_conv<<<dim3(32, 4), 256, 0, stream>>>(x, conv1_w, conv1_b, feat);
    k_gather<<<dim3(1024, 32), 256, 0, stream>>>(feat, xn, baf);
    // GEMM1: scores = baf(32768x704) * attn_wb(1024x704)^T -> att (ldc 1024)
    k_gemm<<<dim3(256 * 8, 1), 256, 0, stream>>>(baf, 0L, 768, attn_wb, 0L, 704,
                                                 att, 0L, 1024, 8, 22);
    k_softmax<<<32768, 256, 0, stream>>>(att, attn_b);
    k_transpose<<<dim3(192, 32), 256, 0, stream>>>(baf, bafT);
    // GEMM2 (batched): att_feat = att(1024x1024) * bafT(768x1024)^T
    k_gemm<<<dim3(8 * 6, 32), 256, 0, stream>>>(att, (long)1024 * 1024, 1024,
                                                bafT, (long)768 * 1024, 1024,
                                                att_feat, (long)1024 * 768, 768, 6, 32);
    k_gemm3<<<256, 256, 0, stream>>>(att_feat, baf, wcat, anchors, cls_b, reg_b, out);
}

// Round 2
// 401.998 us; speedup vs baseline: 1.3562x; 1.3562x over previous
//
#include <hip/hip_runtime.h>

// LaneATT head, MI355X. Pipeline:
//  prep (bf16 weights, x-index table) -> conv1x1 -> gather(baf bf16, padded 1024x768)
//  -> GEMM1 scores (bf16 MFMA, global_load_lds staging) -> softmax+shift (in-place)
//  -> transpose baf -> GEMM2 att_feat -> GEMM3 (cls|reg) + epilogue into d_out.
// ws layout (bytes, 256-aligned), total 221,617,152:
//  feat 0 (1.8M) | xn 1802240 (44K, [11004]=mask-dtype flag) | attn_wb 1846272 (1.44M)
//  | wcat 3288064 (225K) | baf 3513344 (50.3M) | bafT 53844992 (50.3M)
//  | att 104176640 (67.1M) | att_feat 171285504 (50.3M)

typedef unsigned short u16;
typedef short short8 __attribute__((ext_vector_type(8)));
typedef float f32x4 __attribute__((ext_vector_type(4)));

__device__ __forceinline__ u16 f2bf(float f) {
    union { float f; unsigned u; } v; v.f = f;
    unsigned r = v.u + 0x7FFFu + ((v.u >> 16) & 1u);
    return (u16)(r >> 16);
}
__device__ __forceinline__ float bf2f(u16 u) {
    union { unsigned u; float f; } v; v.u = ((unsigned)u) << 16;
    return v.f;
}

// async global->LDS, 16B per lane; lds base must be wave-uniform (HW writes
// lane i at base + i*16B), global address is per-lane.
__device__ __forceinline__ void gload16(const u16* gsrc, u16* ldst) {
    __builtin_amdgcn_global_load_lds(
        (const __attribute__((address_space(1))) unsigned int*)gsrc,
        (__attribute__((address_space(3))) unsigned int*)ldst, 16, 0, 0);
}

// ---------- prep kernels ----------

__global__ __launch_bounds__(256) void k_prep_attnw(const float* __restrict__ attn_w,
                                                    u16* __restrict__ attn_wb) {
    int i = blockIdx.x * 256 + threadIdx.x;          // over 1024*704
    if (i >= 1024 * 704) return;
    int r = i / 704;
    attn_wb[i] = (r < 999) ? f2bf(attn_w[i]) : (u16)0;
}

__global__ __launch_bounds__(256) void k_prep_wcat(const float* __restrict__ cls_w,
                                                   const float* __restrict__ reg_w,
                                                   u16* __restrict__ wcat) {
    int i = blockIdx.x * 256 + threadIdx.x;          // over 80*1408
    if (i >= 80 * 1408) return;
    int o = i / 1408, k = i - o * 1408;
    float v = 0.f;
    if (o < 2) v = cls_w[o * 1408 + k];
    else if (o < 75) v = reg_w[(o - 2) * 1408 + k];
    wcat[i] = f2bf(v);
}

// Detect whether invalid_mask was pushed as bool (1B) or int32 (4B).
__global__ __launch_bounds__(256) void k_detect_mask(const unsigned char* __restrict__ mask,
                                                     int* __restrict__ flag) {
    int any = 0;
    for (int i = threadIdx.x; i < 11000; i += 256)
        if ((i & 3) && mask[i]) any = 1;
    any = __any(any) ? 1 : 0;
    __shared__ int sh[4];
    if ((threadIdx.x & 63) == 0) sh[threadIdx.x >> 6] = any;
    __syncthreads();
    if (threadIdx.x == 0) *flag = sh[0] | sh[1] | sh[2] | sh[3];
}

__global__ __launch_bounds__(256) void k_prep_xn(const int* __restrict__ cut_xs,
                                                 const void* __restrict__ mask,
                                                 const int* __restrict__ flag,
                                                 int* __restrict__ xn) {
    int i = blockIdx.x * 256 + threadIdx.x;          // over 11000 = (n,y)
    if (i >= 11000) return;
    int inv = (*flag) ? (int)((const unsigned char*)mask)[i]
                      : ((const int*)mask)[i];
    int n = i / 11, y = i - n * 11;
    xn[i] = inv ? -1 : cut_xs[n * 704 + y];          // cut_xs[(n*64+0)*11+y]
}

// ---------- conv 1x1 ----------
// grid (32 b, 16 og): block = 256 threads (220 active = pixels), 4 out-ch each.
// x reads coalesced across pixels; 4 independent acc chains + unroll-4 for ILP.
__global__ __launch_bounds__(256) void k_conv(const float* __restrict__ x,
                                              const float* __restrict__ w1,
                                              const float* __restrict__ b1,
                                              float* __restrict__ feat) {
    __shared__ float wl[4][512];
    const int b = blockIdx.x, og = blockIdx.y;
    for (int i = threadIdx.x; i < 4 * 512; i += 256)
        wl[i >> 9][i & 511] = w1[(og * 4 + (i >> 9)) * 512 + (i & 511)];
    __syncthreads();
    const int p = threadIdx.x;
    if (p >= 220) return;
    const float* xb = x + (size_t)b * 512 * 220 + p;
    float a0 = 0.f, a1 = 0.f, a2 = 0.f, a3 = 0.f;
    #pragma unroll 4
    for (int c = 0; c < 512; ++c) {
        float xv = xb[(size_t)c * 220];
        a0 = fmaf(xv, wl[0][c], a0);
        a1 = fmaf(xv, wl[1][c], a1);
        a2 = fmaf(xv, wl[2][c], a2);
        a3 = fmaf(xv, wl[3][c], a3);
    }
    float* fo = feat + (size_t)b * 14080 + (og * 4) * 220 + p;
    fo[0]   = a0 + b1[og * 4 + 0];
    fo[220] = a1 + b1[og * 4 + 1];
    fo[440] = a2 + b1[og * 4 + 2];
    fo[660] = a3 + b1[og * 4 + 3];
}

// ---------- gather -> baf (bf16, [B][1024][768], pads zeroed) ----------
__global__ __launch_bounds__(256) void k_gather(const float* __restrict__ feat,
                                                const int* __restrict__ xn,
                                                u16* __restrict__ baf) {
    int n = blockIdx.x, b = blockIdx.y;
    u16* dst = baf + ((size_t)b * 1024 + n) * 768;
    const float* fb = feat + (size_t)b * 14080;
    for (int d = threadIdx.x; d < 768; d += 256) {
        float v = 0.f;
        if (n < 1000 && d < 704) {
            int c = d / 11, y = d - c * 11;
            int xv = xn[n * 11 + y];
            if (xv >= 0) v = fb[c * 220 + y * 20 + xv];
        }
        dst[d] = f2bf(v);
    }
}

// ---------- generic 128x128 bf16 GEMM, C = A(MxK) * Bt(NrowsxK)^T ----------
// m97 structure: global_load_lds width-16 staging, BK=32, 4 waves, 4x4 acc.
__global__ __launch_bounds__(256) void k_gemm(const u16* __restrict__ A, long sAb, int lda,
                                              const u16* __restrict__ Bt, long sBb, int ldb,
                                              u16* __restrict__ C, long sCb, int ldc,
                                              int ntN, int ksteps) {
    __shared__ __attribute__((aligned(16))) u16 Al[128 * 32];
    __shared__ __attribute__((aligned(16))) u16 Bl[128 * 32];
    A  += (size_t)blockIdx.y * sAb;
    Bt += (size_t)blockIdx.y * sBb;
    C  += (size_t)blockIdx.y * sCb;
    const int tid = threadIdx.x;
    const int tM = blockIdx.x / ntN, tN = blockIdx.x - tM * ntN;
    const int lane = tid & 63, w = tid >> 6;
    const int wr = w >> 1, wc = w & 1;
    const int l15 = lane & 15, lk = (lane >> 4) * 8;

    const u16* Abase = A + (size_t)tM * 128 * lda;
    const u16* Bbase = Bt + (size_t)tN * 128 * ldb;

    // staging addresses: chunk = 16 rows (64 lanes x 16B = 1024B); wave w owns
    // chunks {2w, 2w+1} of each tile. lane covers row lane/4, col-16B lane%4.
    const int sr = lane >> 2, sc = (lane & 3) * 8;

    f32x4 acc[4][4] = {};

    for (int ks = 0; ks < ksteps; ++ks) {
        const int k0 = ks * 32;
        #pragma unroll
        for (int j = 0; j < 2; ++j) {
            const int row = w * 32 + j * 16 + sr;
            gload16(Abase + (size_t)row * lda + k0 + sc, &Al[(w * 32 + j * 16) * 32]);
            gload16(Bbase + (size_t)row * ldb + k0 + sc, &Bl[(w * 32 + j * 16) * 32]);
        }
        __syncthreads();
        short8 af[4], bfr[4];
        #pragma unroll
        for (int m = 0; m < 4; ++m) af[m] = *(const short8*)&Al[(wr * 64 + m * 16 + l15) * 32 + lk];
        #pragma unroll
        for (int n = 0; n < 4; ++n) bfr[n] = *(const short8*)&Bl[(wc * 64 + n * 16 + l15) * 32 + lk];
        #pragma unroll
        for (int m = 0; m < 4; ++m)
            #pragma unroll
            for (int n = 0; n < 4; ++n)
                acc[m][n] = __builtin_amdgcn_mfma_f32_16x16x32_bf16(af[m], bfr[n], acc[m][n], 0, 0, 0);
        __syncthreads();
    }

    const int rb = tM * 128 + wr * 64 + ((lane >> 4) << 2);
    const int cb = tN * 128 + wc * 64 + l15;
    #pragma unroll
    for (int m = 0; m < 4; ++m)
        #pragma unroll
        for (int n = 0; n < 4; ++n)
            #pragma unroll
            for (int j = 0; j < 4; ++j)
                C[(size_t)(rb + m * 16 + j) * ldc + cb + n * 16] = f2bf(acc[m][n][j]);
}

// ---------- softmax + diagonal-shift scatter, in-place on att rows ----------
__global__ __launch_bounds__(256) void k_softmax(u16* __restrict__ att,
                                                 const float* __restrict__ attn_b) {
    __shared__ float sv[1000];
    __shared__ float redm[4], reds[4];
    u16* row = att + (size_t)blockIdx.x * 1024;
    const int n = blockIdx.x & 1023;
    const int tid = threadIdx.x;
    if (n >= 1000) {
        for (int i = tid; i < 1024; i += 256) row[i] = 0;
        return;
    }
    float lmax = -1e30f;
    for (int i = tid; i < 999; i += 256) {
        float v = bf2f(row[i]) + attn_b[i];
        sv[i] = v;
        lmax = fmaxf(lmax, v);
    }
    #pragma unroll
    for (int o = 32; o > 0; o >>= 1) lmax = fmaxf(lmax, __shfl_xor(lmax, o));
    if ((tid & 63) == 0) redm[tid >> 6] = lmax;
    __syncthreads();
    float gmax = fmaxf(fmaxf(redm[0], redm[1]), fmaxf(redm[2], redm[3]));
    float lsum = 0.f;
    for (int i = tid; i < 999; i += 256) {
        float e = __expf(sv[i] - gmax);
        sv[i] = e;
        lsum += e;
    }
    #pragma unroll
    for (int o = 32; o > 0; o >>= 1) lsum += __shfl_xor(lsum, o);
    if ((tid & 63) == 0) reds[tid >> 6] = lsum;
    __syncthreads();
    float inv = 1.f / (reds[0] + reds[1] + reds[2] + reds[3]);
    for (int col = tid; col < 1024; col += 256) {
        u16 v = 0;
        if (col < 1000 && col != n) {
            int m = col - (col > n ? 1 : 0);
            v = f2bf(sv[m] * inv);
        }
        row[col] = v;
    }
}

// ---------- baf transpose: bafT[b][d][m] = baf[b][m][d] ----------
__global__ __launch_bounds__(256) void k_transpose(const u16* __restrict__ baf,
                                                   u16* __restrict__ bafT) {
    __shared__ u16 t[64][65];
    int mt = blockIdx.x & 15, dt = blockIdx.x >> 4;  // 16 m-tiles x 12 d-tiles
    int b = blockIdx.y;
    const u16* src = baf + ((size_t)b * 1024 + mt * 64) * 768 + dt * 64;
    for (int i = threadIdx.x; i < 4096; i += 256) {
        int ml = i >> 6, dl = i & 63;
        t[ml][dl] = src[(size_t)ml * 768 + dl];
    }
    __syncthreads();
    u16* dst = bafT + ((size_t)b * 768 + dt * 64) * 1024 + mt * 64;
    for (int i = threadIdx.x; i < 4096; i += 256) {
        int dl = i >> 6, ml = i & 63;
        dst[(size_t)dl * 1024 + ml] = t[ml][dl];
    }
}

// ---------- final GEMM (all_feat x Wcat^T) + output assembly ----------
__global__ __launch_bounds__(256) void k_gemm3(const u16* __restrict__ AF,
                                               const u16* __restrict__ BAF,
                                               const u16* __restrict__ W,
                                               const float* __restrict__ anchors,
                                               const float* __restrict__ cls_b,
                                               const float* __restrict__ reg_b,
                                               float* __restrict__ out) {
    __shared__ __attribute__((aligned(16))) u16 Al[128 * 32];
    __shared__ __attribute__((aligned(16))) u16 Bl[80 * 32];
    const int tid = threadIdx.x;
    const int tM = blockIdx.x;
    const int lane = tid & 63, w = tid >> 6;
    const int l15 = lane & 15, lk = (lane >> 4) * 8;

    f32x4 acc[2][5] = {};

    for (int ks = 0; ks < 44; ++ks) {
        const u16* Asrc = (ks < 22) ? AF : BAF;
        const int k0 = (ks < 22 ? ks : ks - 22) * 32;
        #pragma unroll
        for (int i = 0; i < 2; ++i) {
            int chunk = i * 256 + tid;
            int row = chunk >> 2, c8 = (chunk & 3) * 8;
            *(short8*)&Al[chunk * 8] =
                *(const short8*)(Asrc + (size_t)(tM * 128 + row) * 768 + k0 + c8);
        }
        {
            int row = tid >> 2, c8 = (tid & 3) * 8;
            *(short8*)&Bl[tid * 8] = *(const short8*)(W + (size_t)row * 1408 + ks * 32 + c8);
            if (tid < 64) {
                int ch2 = 256 + tid;
                int r2 = ch2 >> 2, c82 = (ch2 & 3) * 8;
                *(short8*)&Bl[ch2 * 8] = *(const short8*)(W + (size_t)r2 * 1408 + ks * 32 + c82);
            }
        }
        __syncthreads();
        short8 af[2], bfr[5];
        #pragma unroll
        for (int m = 0; m < 2; ++m) af[m] = *(const short8*)&Al[(w * 32 + m * 16 + l15) * 32 + lk];
        #pragma unroll
        for (int n = 0; n < 5; ++n) bfr[n] = *(const short8*)&Bl[(n * 16 + l15) * 32 + lk];
        #pragma unroll
        for (int m = 0; m < 2; ++m)
            #pragma unroll
            for (int n = 0; n < 5; ++n)
                acc[m][n] = __builtin_amdgcn_mfma_f32_16x16x32_bf16(af[m], bfr[n], acc[m][n], 0, 0, 0);
        __syncthreads();
    }

    #pragma unroll
    for (int m = 0; m < 2; ++m) {
        #pragma unroll
        for (int n = 0; n < 5; ++n) {
            #pragma unroll
            for (int j = 0; j < 4; ++j) {
                int r = tM * 128 + w * 32 + m * 16 + ((lane >> 4) << 2) + j;
                int b = r >> 10, nn = r & 1023;
                if (nn < 1000) {
                    int o = n * 16 + l15;
                    float v = acc[m][n][j];
                    float* orow = out + ((size_t)b * 1000 + nn) * 77;
                    if (o < 2) {
                        orow[o] = v + cls_b[o];
                    } else if (o < 75) {
                        int jj = o - 2;
                        orow[4 + jj] = v + reg_b[jj] + anchors[nn * 77 + 4 + jj];
                        if (o == 2) orow[2] = anchors[nn * 77 + 2];
                        if (o == 3) orow[3] = anchors[nn * 77 + 3];
                    }
                }
            }
        }
    }
}

extern "C" void kernel_launch(void* const* d_in, const int* in_sizes, int n_in,
                              void* d_out, int out_size, void* d_ws, size_t ws_size,
                              hipStream_t stream) {
    const float* x       = (const float*)d_in[0];
    const float* anchors = (const float*)d_in[1];
    const float* conv1_w = (const float*)d_in[2];
    const float* conv1_b = (const float*)d_in[3];
    const float* attn_w  = (const float*)d_in[4];
    const float* attn_b  = (const float*)d_in[5];
    const float* cls_w   = (const float*)d_in[6];
    const float* cls_b   = (const float*)d_in[7];
    const float* reg_w   = (const float*)d_in[8];
    const float* reg_b   = (const float*)d_in[9];
    const int*   cut_xs  = (const int*)d_in[12];
    const void*  invalid = d_in[13];
    float* out = (float*)d_out;

    char* ws = (char*)d_ws;
    float* feat    = (float*)(ws + 0);
    int*   xn      = (int*)  (ws + 1802240);
    int*   mflag   = xn + 11004;
    u16*   attn_wb = (u16*)  (ws + 1846272);
    u16*   wcat    = (u16*)  (ws + 3288064);
    u16*   baf     = (u16*)  (ws + 3513344);
    u16*   bafT    = (u16*)  (ws + 53844992);
    u16*   att     = (u16*)  (ws + 104176640);
    u16*   att_feat= (u16*)  (ws + 171285504);

    k_prep_attnw<<<2816, 256, 0, stream>>>(attn_w, attn_wb);
    k_prep_wcat<<<440, 256, 0, stream>>>(cls_w, reg_w, wcat);
    k_detect_mask<<<1, 256, 0, stream>>>((const unsigned char*)invalid, mflag);
    k_prep_xn<<<43, 256, 0, stream>>>(cut_xs, invalid, mflag, xn);
    k_conv<<<dim3(32, 16), 256, 0, stream>>>(x, conv1_w, conv1_b, feat);
    k_gather<<<dim3(1024, 32), 256, 0, stream>>>(feat, xn, baf);
    // GEMM1: scores = baf(32768x704) * attn_wb(1024x704)^T -> att (ldc 1024)
    k_gemm<<<dim3(256 * 8, 1), 256, 0, stream>>>(baf, 0L, 768, attn_wb, 0L, 704,
                                                 att, 0L, 1024, 8, 22);
    k_softmax<<<32768, 256, 0, stream>>>(att, attn_b);
    k_transpose<<<dim3(192, 32), 256, 0, stream>>>(baf, bafT);
    // GEMM2 (batched): att_feat = att(1024x1024) * bafT(768x1024)^T
    k_gemm<<<dim3(8 * 6, 32), 256, 0, stream>>>(att, (long)1024 * 1024, 1024,
                                                bafT, (long)768 * 1024, 1024,
                                                att_feat, (long)1024 * 768, 768, 6, 32);
    k_gemm3<<<256, 256, 0, stream>>>(att_feat, baf, wcat, anchors, cls_b, reg_b, out);
}